// Round 12
// baseline (117.613 us; speedup 1.0000x reference)
//
#include <hip/hip_runtime.h>
#include <cstdint>

namespace {
constexpr int NWIN = 4096;
constexpr int NT   = 49;
constexpr int D    = 128;
constexpr float SCALE = 0.17677669529663687f;  // 1/sqrt(32)

constexpr int SQ = 136;   // LDS row stride (ushorts)
constexpr int SV = 72;    // fallback kernel only

// wbuf layout (ushort element offsets)
constexpr size_t WQH   = 0;       // qkv_w hi frags (Q cols pre-scaled): 49152
constexpr size_t WOH   = 49152;   // wo_w hi frags: 16384
constexpr size_t WOL   = 65536;   // wo_w lo frags: 16384
constexpr size_t BFRAG = 81920;   // bias frags: 16384
constexpr size_t WBUF_BYTES = 98304 * 2;

// V-frag scratch: per window 8192 ushorts
constexpr size_t VSCR_OFF_USH = 98304;
constexpr size_t TOTAL_WS_BYTES = WBUF_BYTES + (size_t)NWIN * 8192 * 2;  // ~67.3 MB
}

using short8 = __attribute__((ext_vector_type(8))) short;
using f32x4  = __attribute__((ext_vector_type(4))) float;

__device__ __forceinline__ ushort f2bf(float x) {           // round-to-nearest-even
    uint u = __builtin_bit_cast(uint, x);
    uint r = u + 0x7FFFu + ((u >> 16) & 1u);
    return (ushort)(r >> 16);
}
__device__ __forceinline__ ushort f2bf_tr(float x) {        // truncate (damped paths)
    return (ushort)(__builtin_bit_cast(uint, x) >> 16);
}
__device__ __forceinline__ float bf2f(ushort b) {
    uint u = ((uint)b) << 16;
    return __builtin_bit_cast(float, u);
}
__device__ __forceinline__ uint pack_bf2(float a, float b) {
    return ((uint)f2bf(a)) | (((uint)f2bf(b)) << 16);
}

// ---------------- prep: weight frags + bias frags ----------------
__global__ __launch_bounds__(256) void prep_all(
    const float* __restrict__ qkv_w, const float* __restrict__ wo_w,
    const float* __restrict__ bias_table, const int* __restrict__ bias_index,
    ushort* __restrict__ wbuf)
{
    const int blk = blockIdx.x, tid = threadIdx.x;
    if (blk < 96) {
        const int nt = blk >> 2, ks = blk & 3;
        for (int e = tid; e < 512; e += 256) {
            const int lane = e >> 3, j = e & 7;
            const int k = ks * 32 + (lane >> 4) * 8 + j;
            const int n = nt * 16 + (lane & 15);
            float wv = qkv_w[(size_t)k * 384 + n];
            if (n < 128) wv *= SCALE;
            wbuf[WQH + ((size_t)(nt * 4 + ks) * 64 + lane) * 8 + j] = f2bf(wv);
        }
    } else if (blk < 128) {
        const int b2 = blk - 96;
        const int nt = b2 >> 2, ks = b2 & 3;
        for (int e = tid; e < 512; e += 256) {
            const int lane = e >> 3, j = e & 7;
            const int k = ks * 32 + (lane >> 4) * 8 + j;
            const int n = nt * 16 + (lane & 15);
            const float wv = wo_w[(size_t)k * 128 + n];
            const ushort h = f2bf(wv);
            const size_t fo = ((size_t)(nt * 4 + ks) * 64 + lane) * 8 + j;
            wbuf[WOH + fo] = h;
            wbuf[WOL + fo] = f2bf(wv - bf2f(h));
        }
    } else {
        const int p = blk - 128;
        const int h = p >> 2, qt = p & 3;
        for (int ei = tid; ei < 1024; ei += 256) {
            const int lane = ei >> 4, t = (ei >> 2) & 3, r = ei & 3;
            const int q = qt * 16 + (lane & 15);
            const int k = 16 * t + 4 * (lane >> 4) + r;
            float v = 0.f;
            if (q < NT && k < NT) v = bias_table[bias_index[q * NT + k] * 4 + h];
            wbuf[BFRAG + (size_t)p * 1024 + ei] = f2bf(v);
        }
    }
}

// ---------------- fused kernel: 512 threads = 8 waves = TWO windows ----------------
// phase 2: wave = (m-pair = wid>>2, nt-sixth = wid&3 -> 6 nt); each B-frag feeds
//          4 MFMAs (2 windows x 2 m-quarters): qkv-frag traffic 96 KB/window.
// phase 3: wave = (win = wid>>2, head = wid&3), P in registers (unchanged R11)
// phase 4: wave = nt (wid 0..7), both windows: wo-frag traffic 32 KB/window.
// LDS = Q+K x 2 windows = 69632 B -> 2 blocks/CU. V via vscr (L2).
__global__ __launch_bounds__(512, 4) void win2_fused(
    const float* __restrict__ x, const float* __restrict__ qkv_b,
    const ushort* __restrict__ wbuf, const float* __restrict__ wo_b,
    ushort* __restrict__ vscr, float* __restrict__ out)
{
    __shared__ __align__(16) ushort s_q[2][64 * SQ];   // Q (ph2-3), attn-out (ph3-4)
    __shared__ __align__(16) ushort s_k[2][64 * SQ];   // K

    const int b = blockIdx.x, tid = threadIdx.x;       // windows 2b, 2b+1
    const int wid = tid >> 6, lane = tid & 63;
    const int g = lane >> 4, lr = lane & 15;

    // ---- phase 0/2: QKV GEMM ----
    const int mp  = wid >> 2;        // m in {2mp, 2mp+1}
    const int nt0 = (wid & 3) * 6;   // 6 n-tiles

    short8 Ax[2][2][4];              // [win][mi][ks], 64 VGPRs
    #pragma unroll
    for (int wi = 0; wi < 2; ++wi) {
        #pragma unroll
        for (int mi = 0; mi < 2; ++mi) {
            const int row = (2 * mp + mi) * 16 + lr;
            if (row < NT) {
                const float* xr = x + (size_t)(b * 2 + wi) * NT * D + row * D;
                #pragma unroll
                for (int ks = 0; ks < 4; ++ks) {
                    const float4 v0 = *reinterpret_cast<const float4*>(&xr[ks * 32 + g * 8]);
                    const float4 v1 = *reinterpret_cast<const float4*>(&xr[ks * 32 + g * 8 + 4]);
                    uint4 w;
                    w.x = pack_bf2(v0.x, v0.y); w.y = pack_bf2(v0.z, v0.w);
                    w.z = pack_bf2(v1.x, v1.y); w.w = pack_bf2(v1.z, v1.w);
                    Ax[wi][mi][ks] = __builtin_bit_cast(short8, w);
                }
            } else {
                #pragma unroll
                for (int ks = 0; ks < 4; ++ks) Ax[wi][mi][ks] = short8{0,0,0,0,0,0,0,0};
            }
        }
    }
    float qb[6];
    #pragma unroll
    for (int i = 0; i < 6; ++i) {
        const int nt = nt0 + i;
        float v = qkv_b[nt * 16 + lr];
        if (nt < 8) v *= SCALE;
        qb[i] = v;
    }

    #pragma unroll
    for (int i = 0; i < 6; ++i) {                 // nt-inner, acc live only per nt
        const int nt = nt0 + i;
        short8 Bf[4];
        #pragma unroll
        for (int ks = 0; ks < 4; ++ks)
            Bf[ks] = *reinterpret_cast<const short8*>(
                &wbuf[WQH + ((size_t)(nt * 4 + ks) * 64 + lane) * 8]);
        f32x4 acc[2][2] = {};
        #pragma unroll
        for (int ks = 0; ks < 4; ++ks) {
            #pragma unroll
            for (int wi = 0; wi < 2; ++wi) {
                acc[wi][0] = __builtin_amdgcn_mfma_f32_16x16x32_bf16(Ax[wi][0][ks], Bf[ks], acc[wi][0], 0, 0, 0);
                acc[wi][1] = __builtin_amdgcn_mfma_f32_16x16x32_bf16(Ax[wi][1][ks], Bf[ks], acc[wi][1], 0, 0, 0);
            }
        }
        // epilogue for this nt: Q (scaled, trunc) / K (trunc) -> LDS; V -> vscr (RNE)
        const int n = nt * 16 + lr;
        const float bias = qb[i];
        #pragma unroll
        for (int wi = 0; wi < 2; ++wi) {
            #pragma unroll
            for (int mi = 0; mi < 2; ++mi) {
                const int m = 2 * mp + mi;
                if (nt < 16) {
                    ushort* const dst = (nt < 8) ? &s_q[wi][0] : &s_k[wi][0];
                    const int col = n & 127;
                    #pragma unroll
                    for (int jj = 0; jj < 4; ++jj)
                        dst[(m * 16 + g * 4 + jj) * SQ + col] = f2bf_tr(acc[wi][mi][jj] + bias);
                } else {
                    const int d  = n - 256;
                    const int f  = ((d >> 5) * 2 + ((d >> 4) & 1)) * 2 + (m >> 1);
                    const int j0 = 4 * (m & 1);
                    ushort4 hv;
                    #pragma unroll
                    for (int jj = 0; jj < 4; ++jj)
                        (&hv.x)[jj] = f2bf(acc[wi][mi][jj] + bias);   // RNE (un-damped path)
                    ushort* const vw = vscr + (size_t)(b * 2 + wi) * 8192;
                    *reinterpret_cast<ushort4*>(&vw[((size_t)f * 64 + lane) * 8 + j0]) = hv;
                }
            }
        }
    }
    __syncthreads();   // A: Q/K in LDS, V frags in vscr

    // ---- phase 3: wave = (wi3, h); 4 pairs (qt 0..3); P in registers ----
    const int wi3 = wid >> 2;
    const int h   = wid & 3;
    const ushort* const vwp = vscr + (size_t)(b * 2 + wi3) * 8192;
    f32x4 oac[4][2];
    {
        short8 Vf[2][2];
        #pragma unroll
        for (int dt = 0; dt < 2; ++dt)
            #pragma unroll
            for (int ks = 0; ks < 2; ++ks)
                Vf[dt][ks] = *reinterpret_cast<const short8*>(
                    &vwp[((size_t)(((h * 2 + dt) * 2) + ks) * 64 + lane) * 8]);

        #pragma unroll
        for (int pi = 0; pi < 4; ++pi) {
            const int qt = pi;
            const int p  = h * 4 + qt;
            const short8 Qf = *reinterpret_cast<const short8*>(&s_q[wi3][(qt * 16 + lr) * SQ + h * 32 + g * 8]);
            f32x4 sc[4];
            #pragma unroll
            for (int t = 0; t < 4; ++t) {
                const short8 Kf = *reinterpret_cast<const short8*>(&s_k[wi3][(t * 16 + lr) * SQ + h * 32 + g * 8]);
                f32x4 z = {};
                sc[t] = __builtin_amdgcn_mfma_f32_16x16x32_bf16(Kf, Qf, z, 0, 0, 0);
            }
            uint bw[8];
            {
                const uint4 b0 = *reinterpret_cast<const uint4*>(&wbuf[BFRAG + ((size_t)p * 64 + lane) * 16]);
                const uint4 b1 = *reinterpret_cast<const uint4*>(&wbuf[BFRAG + ((size_t)p * 64 + lane) * 16 + 8]);
                bw[0] = b0.x; bw[1] = b0.y; bw[2] = b0.z; bw[3] = b0.w;
                bw[4] = b1.x; bw[5] = b1.y; bw[6] = b1.z; bw[7] = b1.w;
            }
            float ev[16];
            float lsum = 0.f;
            #pragma unroll
            for (int t = 0; t < 4; ++t) {
                #pragma unroll
                for (int r = 0; r < 4; ++r) {
                    const int idx = 4 * t + r;
                    const uint bwv = bw[idx >> 1];
                    const float bv = __builtin_bit_cast(float, (idx & 1) ? (bwv & 0xFFFF0000u) : (bwv << 16));
                    float e;
                    if (t < 3) {
                        e = __expf(sc[t][r] + bv);
                    } else if (r == 0) {
                        e = (g == 0) ? __expf(sc[t][0] + bv) : 0.f;   // k=48 valid only at g==0
                    } else {
                        e = 0.f;
                    }
                    ev[idx] = e;
                    lsum += e;
                }
            }
            lsum += __shfl_xor(lsum, 16);
            lsum += __shfl_xor(lsum, 32);
            const float inv = 1.f / lsum;
            uint pw[8];
            #pragma unroll
            for (int i = 0; i < 8; ++i)
                pw[i] = pack_bf2(ev[2 * i] * inv, ev[2 * i + 1] * inv);   // RNE, normalized
            uint4 w0, w1;
            w0.x = pw[0]; w0.y = pw[1]; w0.z = pw[2]; w0.w = pw[3];
            w1.x = pw[4]; w1.y = pw[5]; w1.z = pw[6]; w1.w = pw[7];
            const short8 pa0 = __builtin_bit_cast(short8, w0);
            const short8 pa1 = __builtin_bit_cast(short8, w1);
            #pragma unroll
            for (int dt = 0; dt < 2; ++dt) {
                f32x4 o = {};
                o = __builtin_amdgcn_mfma_f32_16x16x32_bf16(pa0, Vf[dt][0], o, 0, 0, 0);
                o = __builtin_amdgcn_mfma_f32_16x16x32_bf16(pa1, Vf[dt][1], o, 0, 0, 0);
                oac[pi][dt] = o;
            }
        }
    }
    __syncthreads();   // C: all Q/K LDS reads done -> attn-out may overwrite Q

    #pragma unroll
    for (int pi = 0; pi < 4; ++pi) {
        #pragma unroll
        for (int dt = 0; dt < 2; ++dt) {
            const int d = h * 32 + dt * 16 + lr;
            #pragma unroll
            for (int r = 0; r < 4; ++r) {
                const int q = pi * 16 + 4 * g + r;
                s_q[wi3][q * SQ + d] = f2bf(oac[pi][dt][r]);   // RNE (already normalized)
            }
        }
    }
    __syncthreads();   // D: attn-out ready

    // ---- phase 4: out = attn @ wo_w + wo_b; wave = nt (wid), BOTH windows ----
    {
        const int nt = wid;
        const float wb = wo_b[nt * 16 + lr];
        f32x4 acc[2][4] = {};
        #pragma unroll
        for (int ks = 0; ks < 4; ++ks) {
            const size_t fo = ((size_t)(nt * 4 + ks) * 64 + lane) * 8;
            const short8 Wh = *reinterpret_cast<const short8*>(&wbuf[WOH + fo]);
            const short8 Wl = *reinterpret_cast<const short8*>(&wbuf[WOL + fo]);
            #pragma unroll
            for (int wi = 0; wi < 2; ++wi) {
                #pragma unroll
                for (int mm = 0; mm < 4; ++mm) {
                    const short8 Ah = *reinterpret_cast<const short8*>(
                        &s_q[wi][(mm * 16 + lr) * SQ + ks * 32 + g * 8]);
                    acc[wi][mm] = __builtin_amdgcn_mfma_f32_16x16x32_bf16(Ah, Wh, acc[wi][mm], 0, 0, 0);
                    acc[wi][mm] = __builtin_amdgcn_mfma_f32_16x16x32_bf16(Ah, Wl, acc[wi][mm], 0, 0, 0);
                }
            }
        }
        #pragma unroll
        for (int wi = 0; wi < 2; ++wi) {
            float* ob = out + (size_t)(b * 2 + wi) * NT * D;
            const int n = nt * 16 + lr;
            #pragma unroll
            for (int mm = 0; mm < 4; ++mm) {
                #pragma unroll
                for (int jj = 0; jj < 4; ++jj) {
                    const int q = mm * 16 + 4 * g + jj;
                    if (q < NT) ob[q * D + n] = acc[wi][mm][jj] + wb;
                }
            }
        }
    }
}

// ---------------- fallback: fused kernel, no prep ----------------
__global__ __launch_bounds__(512, 4) void win_attn_np(
    const float* __restrict__ x,
    const float* __restrict__ qkv_w, const float* __restrict__ qkv_b,
    const float* __restrict__ wo_w,  const float* __restrict__ wo_b,
    const float* __restrict__ bias_table, const int* __restrict__ bias_index,
    float* __restrict__ out)
{
    __shared__ __align__(16) ushort s_all[26624];
    ushort* const s_qh = s_all;
    ushort* const s_kh = s_all + 8704;
    ushort* const s_vt = s_all + 17408;

    const int b = blockIdx.x, tid = threadIdx.x;
    const int wid = tid >> 6, lane = tid & 63;
    const int g = lane >> 4, lr = lane & 15;
    const int m = wid >> 1;
    const int nt0 = (wid & 1) * 12;
    const float* xb = x + (size_t)b * NT * D;

    short8 Ax[4];
    {
        const int row = m * 16 + lr;
        if (row < NT) {
            const float* xr = xb + row * D;
            #pragma unroll
            for (int ks = 0; ks < 4; ++ks) {
                const float4 v0 = *reinterpret_cast<const float4*>(&xr[ks * 32 + g * 8]);
                const float4 v1 = *reinterpret_cast<const float4*>(&xr[ks * 32 + g * 8 + 4]);
                uint4 w;
                w.x = pack_bf2(v0.x, v0.y); w.y = pack_bf2(v0.z, v0.w);
                w.z = pack_bf2(v1.x, v1.y); w.w = pack_bf2(v1.z, v1.w);
                Ax[ks] = __builtin_bit_cast(short8, w);
            }
        } else {
            #pragma unroll
            for (int ks = 0; ks < 4; ++ks) Ax[ks] = short8{0,0,0,0,0,0,0,0};
        }
    }
    float qb[12];
    #pragma unroll
    for (int i = 0; i < 12; ++i) {
        const int nt = nt0 + i;
        float v = qkv_b[nt * 16 + lr];
        if (nt < 8) v *= SCALE;
        qb[i] = v;
    }

    #pragma unroll
    for (int pass = 0; pass < 2; ++pass) {
        const int ntb = nt0 + pass * 6;
        f32x4 acc[6] = {};
        #pragma unroll
        for (int ks = 0; ks < 4; ++ks) {
            short8 Bf[6];
            #pragma unroll
            for (int i = 0; i < 6; ++i) {
                #pragma unroll
                for (int j = 0; j < 8; ++j) {
                    float wv = qkv_w[(size_t)(ks * 32 + g * 8 + j) * 384 + (ntb + i) * 16 + lr];
                    if (ntb + i < 8) wv *= SCALE;
                    Bf[i][j] = (short)f2bf(wv);
                }
            }
            #pragma unroll
            for (int i = 0; i < 6; ++i)
                acc[i] = __builtin_amdgcn_mfma_f32_16x16x32_bf16(Ax[ks], Bf[i], acc[i], 0, 0, 0);
        }
        #pragma unroll
        for (int i = 0; i < 6; ++i) {
            const int nt = ntb + i;
            const int n = nt * 16 + lr;
            const float bias = qb[pass * 6 + i];
            if (nt < 16) {
                ushort* const dst = (nt < 8) ? s_qh : s_kh;
                const int col = n & 127;
                #pragma unroll
                for (int jj = 0; jj < 4; ++jj) {
                    const int q = m * 16 + g * 4 + jj;
                    dst[q * SQ + col] = f2bf_tr(acc[i][jj] + bias);
                }
            } else {
                const int d = n - 256;
                const int cbase = 32 * (m >> 1) + 8 * ((4 * m + g) & 3) + 4 * (m & 1);
                ushort4 hv;
                #pragma unroll
                for (int jj = 0; jj < 4; ++jj)
                    (&hv.x)[jj] = f2bf(acc[i][jj] + bias);
                *reinterpret_cast<ushort4*>(&s_vt[d * SV + cbase]) = hv;
            }
        }
    }
    __syncthreads();

    {
        short8 pa[2][2];
        float inv2[2];
        #pragma unroll
        for (int pi = 0; pi < 2; ++pi) {
            const int p = wid * 2 + pi;
            const int h = p >> 2, qt = p & 3;
            uint bw[8];
            {
                const int q = qt * 16 + lr;
                #pragma unroll
                for (int t = 0; t < 4; ++t) {
                    #pragma unroll
                    for (int r = 0; r < 4; r += 2) {
                        const int k0 = 16 * t + 4 * g + r, k1 = k0 + 1;
                        float v0 = 0.f, v1 = 0.f;
                        if (q < NT && k0 < NT) v0 = bias_table[bias_index[q * NT + k0] * 4 + h];
                        if (q < NT && k1 < NT) v1 = bias_table[bias_index[q * NT + k1] * 4 + h];
                        bw[(4 * t + r) >> 1] = ((uint)f2bf(v0)) | (((uint)f2bf(v1)) << 16);
                    }
                }
            }
            const short8 Qf = *reinterpret_cast<const short8*>(&s_qh[(qt * 16 + lr) * SQ + h * 32 + g * 8]);
            f32x4 sc[4];
            #pragma unroll
            for (int t = 0; t < 4; ++t) {
                const short8 Kf = *reinterpret_cast<const short8*>(&s_kh[(t * 16 + lr) * SQ + h * 32 + g * 8]);
                f32x4 z = {};
                sc[t] = __builtin_amdgcn_mfma_f32_16x16x32_bf16(Kf, Qf, z, 0, 0, 0);
            }
            float lsum = 0.f;
            uint pw[8];
            #pragma unroll
            for (int t = 0; t < 4; ++t) {
                float ebits[4];
                #pragma unroll
                for (int r = 0; r < 4; ++r) {
                    const int idx = 4 * t + r;
                    const uint bwv = bw[idx >> 1];
                    const float bv = __builtin_bit_cast(float, (idx & 1) ? (bwv & 0xFFFF0000u) : (bwv << 16));
                    float e;
                    if (t < 3) {
                        e = __expf(sc[t][r] + bv);
                    } else if (r == 0) {
                        e = (g == 0) ? __expf(sc[t][0] + bv) : 0.f;
                    } else {
                        e = 0.f;
                    }
                    const uint tr = __builtin_bit_cast(uint, e) & 0xFFFF0000u;
                    ebits[r] = __builtin_bit_cast(float, tr);
                    lsum += ebits[r];
                }
                pw[t * 2 + 0] = (__builtin_bit_cast(uint, ebits[0]) >> 16) | (__builtin_bit_cast(uint, ebits[1]) & 0xFFFF0000u);
                pw[t * 2 + 1] = (__builtin_bit_cast(uint, ebits[2]) >> 16) | (__builtin_bit_cast(uint, ebits[3]) & 0xFFFF0000u);
            }
            lsum += __shfl_xor(lsum, 16);
            lsum += __shfl_xor(lsum, 32);
            inv2[pi] = 1.f / lsum;
            #pragma unroll
            for (int ks = 0; ks < 2; ++ks) {
                uint4 w;
                w.x = pw[(2 * ks) * 2 + 0]; w.y = pw[(2 * ks) * 2 + 1];
                w.z = pw[(2 * ks + 1) * 2 + 0]; w.w = pw[(2 * ks + 1) * 2 + 1];
                pa[pi][ks] = __builtin_bit_cast(short8, w);
            }
        }

        f32x4 oac[2][2];
        #pragma unroll
        for (int pi = 0; pi < 2; ++pi) {
            const int p = wid * 2 + pi;
            const int h = p >> 2;
            #pragma unroll
            for (int dt = 0; dt < 2; ++dt) {
                f32x4 o = {};
                #pragma unroll
                for (int ks = 0; ks < 2; ++ks) {
                    const short8 Vf = *reinterpret_cast<const short8*>(&s_vt[(h * 32 + dt * 16 + lr) * SV + ks * 32 + g * 8]);
                    o = __builtin_amdgcn_mfma_f32_16x16x32_bf16(pa[pi][ks], Vf, o, 0, 0, 0);
                }
                oac[pi][dt] = o;
            }
        }
        __syncthreads();

        #pragma unroll
        for (int pi = 0; pi < 2; ++pi) {
            const int p = wid * 2 + pi;
            const int h = p >> 2, qt = p & 3;
            #pragma unroll
            for (int dt = 0; dt < 2; ++dt) {
                const int d = h * 32 + dt * 16 + lr;
                #pragma unroll
                for (int r = 0; r < 4; ++r) {
                    const float inv = __shfl(inv2[pi], 4 * g + r);
                    const int q = qt * 16 + 4 * g + r;
                    s_qh[q * SQ + d] = f2bf(oac[pi][dt][r] * inv);
                }
            }
        }
    }
    __syncthreads();

    {
        const int nt04 = (wid & 1) * 4;
        float wb4[4];
        #pragma unroll
        for (int i = 0; i < 4; ++i) wb4[i] = wo_b[(nt04 + i) * 16 + lr];
        f32x4 acc[4] = {};
        #pragma unroll
        for (int ks = 0; ks < 4; ++ks) {
            short8 Wh[4], Wl[4];
            #pragma unroll
            for (int i = 0; i < 4; ++i) {
                #pragma unroll
                for (int j = 0; j < 8; ++j) {
                    const float wv = wo_w[(size_t)(ks * 32 + g * 8 + j) * 128 + (nt04 + i) * 16 + lr];
                    const ushort hh = f2bf(wv);
                    Wh[i][j] = (short)hh;
                    Wl[i][j] = (short)f2bf(wv - bf2f(hh));
                }
            }
            const short8 Ah = *reinterpret_cast<const short8*>(&s_qh[(m * 16 + lr) * SQ + ks * 32 + g * 8]);
            #pragma unroll
            for (int i = 0; i < 4; ++i) {
                acc[i] = __builtin_amdgcn_mfma_f32_16x16x32_bf16(Ah, Wh[i], acc[i], 0, 0, 0);
                acc[i] = __builtin_amdgcn_mfma_f32_16x16x32_bf16(Ah, Wl[i], acc[i], 0, 0, 0);
            }
        }
        float* ob = out + (size_t)b * NT * D;
        #pragma unroll
        for (int i = 0; i < 4; ++i) {
            const int n = (nt04 + i) * 16 + lr;
            #pragma unroll
            for (int jj = 0; jj < 4; ++jj) {
                const int q = m * 16 + g * 4 + jj;
                if (q < NT) ob[q * D + n] = acc[i][jj] + wb4[i];
            }
        }
    }
}

extern "C" void kernel_launch(void* const* d_in, const int* in_sizes, int n_in,
                              void* d_out, int out_size, void* d_ws, size_t ws_size,
                              hipStream_t stream) {
    const float* x          = (const float*)d_in[0];
    const float* qkv_w      = (const float*)d_in[1];
    const float* qkv_b      = (const float*)d_in[2];
    const float* wo_w       = (const float*)d_in[3];
    const float* wo_b       = (const float*)d_in[4];
    const float* bias_table = (const float*)d_in[5];
    const int*   bias_index = (const int*)d_in[6];
    float* outp = (float*)d_out;

    if (ws_size >= TOTAL_WS_BYTES) {
        ushort* wbuf = (ushort*)d_ws;
        ushort* vscr = wbuf + VSCR_OFF_USH;
        prep_all<<<dim3(144), dim3(256), 0, stream>>>(qkv_w, wo_w, bias_table, bias_index, wbuf);
        win2_fused<<<dim3(NWIN / 2), dim3(512), 0, stream>>>(x, qkv_b, wbuf, wo_b, vscr, outp);
    } else {
        win_attn_np<<<dim3(NWIN), dim3(512), 0, stream>>>(
            x, qkv_w, qkv_b, wo_w, wo_b, bias_table, bias_index, outp);
    }
}

// Round 13
// 103.829 us; speedup vs baseline: 1.1328x; 1.1328x over previous
//
#include <hip/hip_runtime.h>
#include <cstdint>

namespace {
constexpr int NWIN = 4096;
constexpr int NT   = 49;
constexpr int D    = 128;
constexpr float SCALE = 0.17677669529663687f;  // 1/sqrt(32)

constexpr int SQ = 136;   // LDS row stride (ushorts)
constexpr int SV = 72;    // fallback kernel only

// wbuf layout (ushort element offsets)
constexpr size_t WQH   = 0;       // qkv_w hi frags (Q cols pre-scaled): 49152
constexpr size_t WOH   = 49152;   // wo_w hi frags: 16384
constexpr size_t WOL   = 65536;   // wo_w lo frags: 16384
constexpr size_t BFRAG = 81920;   // bias frags: 16384
constexpr size_t WBUF_BYTES = 98304 * 2;

// V-frag scratch: per window 8192 ushorts
constexpr size_t VSCR_OFF_USH = 98304;
constexpr size_t TOTAL_WS_BYTES = WBUF_BYTES + (size_t)NWIN * 8192 * 2;  // ~67.3 MB
}

using short8 = __attribute__((ext_vector_type(8))) short;
using f32x4  = __attribute__((ext_vector_type(4))) float;

__device__ __forceinline__ ushort f2bf(float x) {           // software RNE (prep/fallback)
    uint u = __builtin_bit_cast(uint, x);
    uint r = u + 0x7FFFu + ((u >> 16) & 1u);
    return (ushort)(r >> 16);
}
__device__ __forceinline__ ushort f2bf_tr(float x) {        // truncate (damped paths)
    return (ushort)(__builtin_bit_cast(uint, x) >> 16);
}
__device__ __forceinline__ float bf2f(ushort b) {
    uint u = ((uint)b) << 16;
    return __builtin_bit_cast(float, u);
}
__device__ __forceinline__ uint pack_bf2(float a, float b) { // software packed RNE (fallback)
    return ((uint)f2bf(a)) | (((uint)f2bf(b)) << 16);
}
// hardware packed RNE: dst = { lo: bf16(a), hi: bf16(b) } in ONE VALU op
__device__ __forceinline__ uint cvt_pk_bf16(float a, float b) {
    uint r;
    asm("v_cvt_pk_bf16_f32 %0, %1, %2" : "=v"(r) : "v"(a), "v"(b));
    return r;
}

// ---------------- prep: weight frags + bias frags ----------------
__global__ __launch_bounds__(256) void prep_all(
    const float* __restrict__ qkv_w, const float* __restrict__ wo_w,
    const float* __restrict__ bias_table, const int* __restrict__ bias_index,
    ushort* __restrict__ wbuf)
{
    const int blk = blockIdx.x, tid = threadIdx.x;
    if (blk < 96) {
        const int nt = blk >> 2, ks = blk & 3;
        for (int e = tid; e < 512; e += 256) {
            const int lane = e >> 3, j = e & 7;
            const int k = ks * 32 + (lane >> 4) * 8 + j;
            const int n = nt * 16 + (lane & 15);
            float wv = qkv_w[(size_t)k * 384 + n];
            if (n < 128) wv *= SCALE;
            wbuf[WQH + ((size_t)(nt * 4 + ks) * 64 + lane) * 8 + j] = f2bf(wv);
        }
    } else if (blk < 128) {
        const int b2 = blk - 96;
        const int nt = b2 >> 2, ks = b2 & 3;
        for (int e = tid; e < 512; e += 256) {
            const int lane = e >> 3, j = e & 7;
            const int k = ks * 32 + (lane >> 4) * 8 + j;
            const int n = nt * 16 + (lane & 15);
            const float wv = wo_w[(size_t)k * 128 + n];
            const ushort h = f2bf(wv);
            const size_t fo = ((size_t)(nt * 4 + ks) * 64 + lane) * 8 + j;
            wbuf[WOH + fo] = h;
            wbuf[WOL + fo] = f2bf(wv - bf2f(h));
        }
    } else {
        const int p = blk - 128;
        const int h = p >> 2, qt = p & 3;
        for (int ei = tid; ei < 1024; ei += 256) {
            const int lane = ei >> 4, t = (ei >> 2) & 3, r = ei & 3;
            const int q = qt * 16 + (lane & 15);
            const int k = 16 * t + 4 * (lane >> 4) + r;
            float v = 0.f;
            if (q < NT && k < NT) v = bias_table[bias_index[q * NT + k] * 4 + h];
            wbuf[BFRAG + (size_t)p * 1024 + ei] = f2bf(v);
        }
    }
}

// ---------------- fused kernel: 512 threads = 8 waves = TWO windows (R11 structure) ----------------
// phase 2: wave = (m = wid>>1, nt-half = wid&1), both windows share B-frags (AI=2)
// phase 3: wave = (win = wid>>2, head = wid&3), P in registers
// phase 4: wave = (win = wid>>2, ntp = wid&3 -> nt {ntp, ntp+4}), AI=4 on wo frags
// LDS = Q+K x 2 windows = 69632 B -> 2 blocks/CU. V via vscr (L2).
// R13 delta vs R11: all RNE bf16 conversions use hardware v_cvt_pk_bf16_f32.
__global__ __launch_bounds__(512, 4) void win2_fused(
    const float* __restrict__ x, const float* __restrict__ qkv_b,
    const ushort* __restrict__ wbuf, const float* __restrict__ wo_b,
    ushort* __restrict__ vscr, float* __restrict__ out)
{
    __shared__ __align__(16) ushort s_q[2][64 * SQ];   // Q (ph2-3), attn-out (ph3-4)
    __shared__ __align__(16) ushort s_k[2][64 * SQ];   // K

    const int b = blockIdx.x, tid = threadIdx.x;       // windows 2b, 2b+1
    const int wid = tid >> 6, lane = tid & 63;
    const int g = lane >> 4, lr = lane & 15;

    // ---- phase 0/2: QKV GEMM ----
    const int m = wid >> 1;          // token-quarter
    const int nt0 = (wid & 1) * 12;  // nt half

    short8 Ax[2][4];
    {
        const int row = m * 16 + lr;
        #pragma unroll
        for (int wi = 0; wi < 2; ++wi) {
            if (row < NT) {
                const float* xr = x + (size_t)(b * 2 + wi) * NT * D + row * D;
                #pragma unroll
                for (int ks = 0; ks < 4; ++ks) {
                    const float4 v0 = *reinterpret_cast<const float4*>(&xr[ks * 32 + g * 8]);
                    const float4 v1 = *reinterpret_cast<const float4*>(&xr[ks * 32 + g * 8 + 4]);
                    uint4 w;
                    w.x = cvt_pk_bf16(v0.x, v0.y); w.y = cvt_pk_bf16(v0.z, v0.w);
                    w.z = cvt_pk_bf16(v1.x, v1.y); w.w = cvt_pk_bf16(v1.z, v1.w);
                    Ax[wi][ks] = __builtin_bit_cast(short8, w);
                }
            } else {
                #pragma unroll
                for (int ks = 0; ks < 4; ++ks) Ax[wi][ks] = short8{0,0,0,0,0,0,0,0};
            }
        }
    }
    float qb[12];
    #pragma unroll
    for (int i = 0; i < 12; ++i) {
        const int nt = nt0 + i;
        float v = qkv_b[nt * 16 + lr];
        if (nt < 8) v *= SCALE;
        qb[i] = v;
    }

    #pragma unroll
    for (int pass = 0; pass < 4; ++pass) {     // 3 nt per pass
        const int ntb = nt0 + pass * 3;
        f32x4 acc[2][3] = {};
        #pragma unroll
        for (int ks = 0; ks < 4; ++ks) {
            short8 Bf[3];
            #pragma unroll
            for (int i = 0; i < 3; ++i)
                Bf[i] = *reinterpret_cast<const short8*>(
                    &wbuf[WQH + ((size_t)((ntb + i) * 4 + ks) * 64 + lane) * 8]);
            #pragma unroll
            for (int i = 0; i < 3; ++i) {
                acc[0][i] = __builtin_amdgcn_mfma_f32_16x16x32_bf16(Ax[0][ks], Bf[i], acc[0][i], 0, 0, 0);
                acc[1][i] = __builtin_amdgcn_mfma_f32_16x16x32_bf16(Ax[1][ks], Bf[i], acc[1][i], 0, 0, 0);
            }
        }
        // epilogue: Q (scaled, trunc) / K (trunc) -> LDS; V -> vscr frags (HW RNE)
        #pragma unroll
        for (int i = 0; i < 3; ++i) {
            const int nt = ntb + i;
            const int n = nt * 16 + lr;
            const float bias = qb[pass * 3 + i];
            #pragma unroll
            for (int wi = 0; wi < 2; ++wi) {
                if (nt < 16) {
                    ushort* const dst = (nt < 8) ? &s_q[wi][0] : &s_k[wi][0];
                    const int col = n & 127;
                    #pragma unroll
                    for (int jj = 0; jj < 4; ++jj)
                        dst[(m * 16 + g * 4 + jj) * SQ + col] = f2bf_tr(acc[wi][i][jj] + bias);
                } else {
                    const int d  = n - 256;
                    const int f  = ((d >> 5) * 2 + ((d >> 4) & 1)) * 2 + (m >> 1);
                    const int j0 = 4 * (m & 1);
                    const float b0 = acc[wi][i][0] + bias, b1 = acc[wi][i][1] + bias;
                    const float b2 = acc[wi][i][2] + bias, b3 = acc[wi][i][3] + bias;
                    uint2 hv;
                    hv.x = cvt_pk_bf16(b0, b1);
                    hv.y = cvt_pk_bf16(b2, b3);
                    ushort* const vw = vscr + (size_t)(b * 2 + wi) * 8192;
                    *reinterpret_cast<uint2*>(&vw[((size_t)f * 64 + lane) * 8 + j0]) = hv;
                }
            }
        }
    }
    __syncthreads();   // A: Q/K in LDS, V frags in vscr

    // ---- phase 3: wave = (wi3, h); 4 pairs (qt 0..3); P in registers ----
    const int wi3 = wid >> 2;
    const int h   = wid & 3;
    const ushort* const vwp = vscr + (size_t)(b * 2 + wi3) * 8192;
    f32x4 oac[4][2];
    {
        short8 Vf[2][2];
        #pragma unroll
        for (int dt = 0; dt < 2; ++dt)
            #pragma unroll
            for (int ks = 0; ks < 2; ++ks)
                Vf[dt][ks] = *reinterpret_cast<const short8*>(
                    &vwp[((size_t)(((h * 2 + dt) * 2) + ks) * 64 + lane) * 8]);

        #pragma unroll
        for (int pi = 0; pi < 4; ++pi) {
            const int qt = pi;
            const int p  = h * 4 + qt;
            const short8 Qf = *reinterpret_cast<const short8*>(&s_q[wi3][(qt * 16 + lr) * SQ + h * 32 + g * 8]);
            f32x4 sc[4];
            #pragma unroll
            for (int t = 0; t < 4; ++t) {
                const short8 Kf = *reinterpret_cast<const short8*>(&s_k[wi3][(t * 16 + lr) * SQ + h * 32 + g * 8]);
                f32x4 z = {};
                sc[t] = __builtin_amdgcn_mfma_f32_16x16x32_bf16(Kf, Qf, z, 0, 0, 0);
            }
            uint bw[8];
            {
                const uint4 b0 = *reinterpret_cast<const uint4*>(&wbuf[BFRAG + ((size_t)p * 64 + lane) * 16]);
                const uint4 b1 = *reinterpret_cast<const uint4*>(&wbuf[BFRAG + ((size_t)p * 64 + lane) * 16 + 8]);
                bw[0] = b0.x; bw[1] = b0.y; bw[2] = b0.z; bw[3] = b0.w;
                bw[4] = b1.x; bw[5] = b1.y; bw[6] = b1.z; bw[7] = b1.w;
            }
            float ev[16];
            float lsum = 0.f;
            #pragma unroll
            for (int t = 0; t < 4; ++t) {
                #pragma unroll
                for (int r = 0; r < 4; ++r) {
                    const int idx = 4 * t + r;
                    const uint bwv = bw[idx >> 1];
                    const float bv = __builtin_bit_cast(float, (idx & 1) ? (bwv & 0xFFFF0000u) : (bwv << 16));
                    float e;
                    if (t < 3) {
                        e = __expf(sc[t][r] + bv);
                    } else if (r == 0) {
                        e = (g == 0) ? __expf(sc[t][0] + bv) : 0.f;   // k=48 valid only at g==0
                    } else {
                        e = 0.f;
                    }
                    ev[idx] = e;
                    lsum += e;
                }
            }
            lsum += __shfl_xor(lsum, 16);
            lsum += __shfl_xor(lsum, 32);
            const float inv = 1.f / lsum;
            uint pw[8];
            #pragma unroll
            for (int i = 0; i < 8; ++i)
                pw[i] = cvt_pk_bf16(ev[2 * i] * inv, ev[2 * i + 1] * inv);   // HW RNE, normalized
            uint4 w0, w1;
            w0.x = pw[0]; w0.y = pw[1]; w0.z = pw[2]; w0.w = pw[3];
            w1.x = pw[4]; w1.y = pw[5]; w1.z = pw[6]; w1.w = pw[7];
            const short8 pa0 = __builtin_bit_cast(short8, w0);
            const short8 pa1 = __builtin_bit_cast(short8, w1);
            #pragma unroll
            for (int dt = 0; dt < 2; ++dt) {
                f32x4 o = {};
                o = __builtin_amdgcn_mfma_f32_16x16x32_bf16(pa0, Vf[dt][0], o, 0, 0, 0);
                o = __builtin_amdgcn_mfma_f32_16x16x32_bf16(pa1, Vf[dt][1], o, 0, 0, 0);
                oac[pi][dt] = o;
            }
        }
    }
    __syncthreads();   // C: all Q/K LDS reads done -> attn-out may overwrite Q

    #pragma unroll
    for (int pi = 0; pi < 4; ++pi) {
        #pragma unroll
        for (int dt = 0; dt < 2; ++dt) {
            const int d = h * 32 + dt * 16 + lr;
            #pragma unroll
            for (int r = 0; r < 4; r += 2) {
                const uint u = cvt_pk_bf16(oac[pi][dt][r], oac[pi][dt][r + 1]);  // HW RNE
                const int q0 = pi * 16 + 4 * g + r;
                s_q[wi3][q0 * SQ + d]       = (ushort)u;
                s_q[wi3][(q0 + 1) * SQ + d] = (ushort)(u >> 16);
            }
        }
    }
    __syncthreads();   // D: attn-out ready

    // ---- phase 4: out = attn @ wo_w + wo_b; wave = (wi4, nt {ntp, ntp+4}) ----
    {
        const int wi4 = wid >> 2;
        const int ntp = wid & 3;
        float wb2[2];
        wb2[0] = wo_b[ntp * 16 + lr];
        wb2[1] = wo_b[(ntp + 4) * 16 + lr];
        f32x4 acc[2][4] = {};
        #pragma unroll
        for (int ks = 0; ks < 4; ++ks) {
            short8 Ah[4];
            #pragma unroll
            for (int mm = 0; mm < 4; ++mm)
                Ah[mm] = *reinterpret_cast<const short8*>(&s_q[wi4][(mm * 16 + lr) * SQ + ks * 32 + g * 8]);
            #pragma unroll
            for (int i = 0; i < 2; ++i) {
                const int nt = ntp + i * 4;
                const size_t fo = ((size_t)(nt * 4 + ks) * 64 + lane) * 8;
                const short8 Wh = *reinterpret_cast<const short8*>(&wbuf[WOH + fo]);
                const short8 Wl = *reinterpret_cast<const short8*>(&wbuf[WOL + fo]);
                #pragma unroll
                for (int mm = 0; mm < 4; ++mm) {
                    acc[i][mm] = __builtin_amdgcn_mfma_f32_16x16x32_bf16(Ah[mm], Wh, acc[i][mm], 0, 0, 0);
                    acc[i][mm] = __builtin_amdgcn_mfma_f32_16x16x32_bf16(Ah[mm], Wl, acc[i][mm], 0, 0, 0);
                }
            }
        }
        float* ob = out + (size_t)(b * 2 + wi4) * NT * D;
        #pragma unroll
        for (int i = 0; i < 2; ++i) {
            const int n = (ntp + i * 4) * 16 + lr;
            #pragma unroll
            for (int mm = 0; mm < 4; ++mm) {
                #pragma unroll
                for (int jj = 0; jj < 4; ++jj) {
                    const int q = mm * 16 + 4 * g + jj;
                    if (q < NT) ob[q * D + n] = acc[i][mm][jj] + wb2[i];
                }
            }
        }
    }
}

// ---------------- fallback: fused kernel, no prep ----------------
__global__ __launch_bounds__(512, 4) void win_attn_np(
    const float* __restrict__ x,
    const float* __restrict__ qkv_w, const float* __restrict__ qkv_b,
    const float* __restrict__ wo_w,  const float* __restrict__ wo_b,
    const float* __restrict__ bias_table, const int* __restrict__ bias_index,
    float* __restrict__ out)
{
    __shared__ __align__(16) ushort s_all[26624];
    ushort* const s_qh = s_all;
    ushort* const s_kh = s_all + 8704;
    ushort* const s_vt = s_all + 17408;

    const int b = blockIdx.x, tid = threadIdx.x;
    const int wid = tid >> 6, lane = tid & 63;
    const int g = lane >> 4, lr = lane & 15;
    const int m = wid >> 1;
    const int nt0 = (wid & 1) * 12;
    const float* xb = x + (size_t)b * NT * D;

    short8 Ax[4];
    {
        const int row = m * 16 + lr;
        if (row < NT) {
            const float* xr = xb + row * D;
            #pragma unroll
            for (int ks = 0; ks < 4; ++ks) {
                const float4 v0 = *reinterpret_cast<const float4*>(&xr[ks * 32 + g * 8]);
                const float4 v1 = *reinterpret_cast<const float4*>(&xr[ks * 32 + g * 8 + 4]);
                uint4 w;
                w.x = pack_bf2(v0.x, v0.y); w.y = pack_bf2(v0.z, v0.w);
                w.z = pack_bf2(v1.x, v1.y); w.w = pack_bf2(v1.z, v1.w);
                Ax[ks] = __builtin_bit_cast(short8, w);
            }
        } else {
            #pragma unroll
            for (int ks = 0; ks < 4; ++ks) Ax[ks] = short8{0,0,0,0,0,0,0,0};
        }
    }
    float qb[12];
    #pragma unroll
    for (int i = 0; i < 12; ++i) {
        const int nt = nt0 + i;
        float v = qkv_b[nt * 16 + lr];
        if (nt < 8) v *= SCALE;
        qb[i] = v;
    }

    #pragma unroll
    for (int pass = 0; pass < 2; ++pass) {
        const int ntb = nt0 + pass * 6;
        f32x4 acc[6] = {};
        #pragma unroll
        for (int ks = 0; ks < 4; ++ks) {
            short8 Bf[6];
            #pragma unroll
            for (int i = 0; i < 6; ++i) {
                #pragma unroll
                for (int j = 0; j < 8; ++j) {
                    float wv = qkv_w[(size_t)(ks * 32 + g * 8 + j) * 384 + (ntb + i) * 16 + lr];
                    if (ntb + i < 8) wv *= SCALE;
                    Bf[i][j] = (short)f2bf(wv);
                }
            }
            #pragma unroll
            for (int i = 0; i < 6; ++i)
                acc[i] = __builtin_amdgcn_mfma_f32_16x16x32_bf16(Ax[ks], Bf[i], acc[i], 0, 0, 0);
        }
        #pragma unroll
        for (int i = 0; i < 6; ++i) {
            const int nt = ntb + i;
            const int n = nt * 16 + lr;
            const float bias = qb[pass * 6 + i];
            if (nt < 16) {
                ushort* const dst = (nt < 8) ? s_qh : s_kh;
                const int col = n & 127;
                #pragma unroll
                for (int jj = 0; jj < 4; ++jj) {
                    const int q = m * 16 + g * 4 + jj;
                    dst[q * SQ + col] = f2bf_tr(acc[i][jj] + bias);
                }
            } else {
                const int d = n - 256;
                const int cbase = 32 * (m >> 1) + 8 * ((4 * m + g) & 3) + 4 * (m & 1);
                ushort4 hv;
                #pragma unroll
                for (int jj = 0; jj < 4; ++jj)
                    (&hv.x)[jj] = f2bf(acc[i][jj] + bias);
                *reinterpret_cast<ushort4*>(&s_vt[d * SV + cbase]) = hv;
            }
        }
    }
    __syncthreads();

    {
        short8 pa[2][2];
        float inv2[2];
        #pragma unroll
        for (int pi = 0; pi < 2; ++pi) {
            const int p = wid * 2 + pi;
            const int h = p >> 2, qt = p & 3;
            uint bw[8];
            {
                const int q = qt * 16 + lr;
                #pragma unroll
                for (int t = 0; t < 4; ++t) {
                    #pragma unroll
                    for (int r = 0; r < 4; r += 2) {
                        const int k0 = 16 * t + 4 * g + r, k1 = k0 + 1;
                        float v0 = 0.f, v1 = 0.f;
                        if (q < NT && k0 < NT) v0 = bias_table[bias_index[q * NT + k0] * 4 + h];
                        if (q < NT && k1 < NT) v1 = bias_table[bias_index[q * NT + k1] * 4 + h];
                        bw[(4 * t + r) >> 1] = ((uint)f2bf(v0)) | (((uint)f2bf(v1)) << 16);
                    }
                }
            }
            const short8 Qf = *reinterpret_cast<const short8*>(&s_qh[(qt * 16 + lr) * SQ + h * 32 + g * 8]);
            f32x4 sc[4];
            #pragma unroll
            for (int t = 0; t < 4; ++t) {
                const short8 Kf = *reinterpret_cast<const short8*>(&s_kh[(t * 16 + lr) * SQ + h * 32 + g * 8]);
                f32x4 z = {};
                sc[t] = __builtin_amdgcn_mfma_f32_16x16x32_bf16(Kf, Qf, z, 0, 0, 0);
            }
            float lsum = 0.f;
            uint pw[8];
            #pragma unroll
            for (int t = 0; t < 4; ++t) {
                float ebits[4];
                #pragma unroll
                for (int r = 0; r < 4; ++r) {
                    const int idx = 4 * t + r;
                    const uint bwv = bw[idx >> 1];
                    const float bv = __builtin_bit_cast(float, (idx & 1) ? (bwv & 0xFFFF0000u) : (bwv << 16));
                    float e;
                    if (t < 3) {
                        e = __expf(sc[t][r] + bv);
                    } else if (r == 0) {
                        e = (g == 0) ? __expf(sc[t][0] + bv) : 0.f;
                    } else {
                        e = 0.f;
                    }
                    const uint tr = __builtin_bit_cast(uint, e) & 0xFFFF0000u;
                    ebits[r] = __builtin_bit_cast(float, tr);
                    lsum += ebits[r];
                }
                pw[t * 2 + 0] = (__builtin_bit_cast(uint, ebits[0]) >> 16) | (__builtin_bit_cast(uint, ebits[1]) & 0xFFFF0000u);
                pw[t * 2 + 1] = (__builtin_bit_cast(uint, ebits[2]) >> 16) | (__builtin_bit_cast(uint, ebits[3]) & 0xFFFF0000u);
            }
            lsum += __shfl_xor(lsum, 16);
            lsum += __shfl_xor(lsum, 32);
            inv2[pi] = 1.f / lsum;
            #pragma unroll
            for (int ks = 0; ks < 2; ++ks) {
                uint4 w;
                w.x = pw[(2 * ks) * 2 + 0]; w.y = pw[(2 * ks) * 2 + 1];
                w.z = pw[(2 * ks + 1) * 2 + 0]; w.w = pw[(2 * ks + 1) * 2 + 1];
                pa[pi][ks] = __builtin_bit_cast(short8, w);
            }
        }

        f32x4 oac[2][2];
        #pragma unroll
        for (int pi = 0; pi < 2; ++pi) {
            const int p = wid * 2 + pi;
            const int h = p >> 2;
            #pragma unroll
            for (int dt = 0; dt < 2; ++dt) {
                f32x4 o = {};
                #pragma unroll
                for (int ks = 0; ks < 2; ++ks) {
                    const short8 Vf = *reinterpret_cast<const short8*>(&s_vt[(h * 32 + dt * 16 + lr) * SV + ks * 32 + g * 8]);
                    o = __builtin_amdgcn_mfma_f32_16x16x32_bf16(pa[pi][ks], Vf, o, 0, 0, 0);
                }
                oac[pi][dt] = o;
            }
        }
        __syncthreads();

        #pragma unroll
        for (int pi = 0; pi < 2; ++pi) {
            const int p = wid * 2 + pi;
            const int h = p >> 2, qt = p & 3;
            #pragma unroll
            for (int dt = 0; dt < 2; ++dt) {
                const int d = h * 32 + dt * 16 + lr;
                #pragma unroll
                for (int r = 0; r < 4; ++r) {
                    const float inv = __shfl(inv2[pi], 4 * g + r);
                    const int q = qt * 16 + 4 * g + r;
                    s_qh[q * SQ + d] = f2bf(oac[pi][dt][r] * inv);
                }
            }
        }
    }
    __syncthreads();

    {
        const int nt04 = (wid & 1) * 4;
        float wb4[4];
        #pragma unroll
        for (int i = 0; i < 4; ++i) wb4[i] = wo_b[(nt04 + i) * 16 + lr];
        f32x4 acc[4] = {};
        #pragma unroll
        for (int ks = 0; ks < 4; ++ks) {
            short8 Wh[4], Wl[4];
            #pragma unroll
            for (int i = 0; i < 4; ++i) {
                #pragma unroll
                for (int j = 0; j < 8; ++j) {
                    const float wv = wo_w[(size_t)(ks * 32 + g * 8 + j) * 128 + (nt04 + i) * 16 + lr];
                    const ushort hh = f2bf(wv);
                    Wh[i][j] = (short)hh;
                    Wl[i][j] = (short)f2bf(wv - bf2f(hh));
                }
            }
            const short8 Ah = *reinterpret_cast<const short8*>(&s_qh[(m * 16 + lr) * SQ + ks * 32 + g * 8]);
            #pragma unroll
            for (int i = 0; i < 4; ++i) {
                acc[i] = __builtin_amdgcn_mfma_f32_16x16x32_bf16(Ah, Wh[i], acc[i], 0, 0, 0);
                acc[i] = __builtin_amdgcn_mfma_f32_16x16x32_bf16(Ah, Wl[i], acc[i], 0, 0, 0);
            }
        }
        float* ob = out + (size_t)b * NT * D;
        #pragma unroll
        for (int i = 0; i < 4; ++i) {
            const int n = (nt04 + i) * 16 + lr;
            #pragma unroll
            for (int jj = 0; jj < 4; ++jj) {
                const int q = m * 16 + g * 4 + jj;
                if (q < NT) ob[q * D + n] = acc[i][jj] + wb4[i];
            }
        }
    }
}

extern "C" void kernel_launch(void* const* d_in, const int* in_sizes, int n_in,
                              void* d_out, int out_size, void* d_ws, size_t ws_size,
                              hipStream_t stream) {
    const float* x          = (const float*)d_in[0];
    const float* qkv_w      = (const float*)d_in[1];
    const float* qkv_b      = (const float*)d_in[2];
    const float* wo_w       = (const float*)d_in[3];
    const float* wo_b       = (const float*)d_in[4];
    const float* bias_table = (const float*)d_in[5];
    const int*   bias_index = (const int*)d_in[6];
    float* outp = (float*)d_out;

    if (ws_size >= TOTAL_WS_BYTES) {
        ushort* wbuf = (ushort*)d_ws;
        ushort* vscr = wbuf + VSCR_OFF_USH;
        prep_all<<<dim3(144), dim3(256), 0, stream>>>(qkv_w, wo_w, bias_table, bias_index, wbuf);
        win2_fused<<<dim3(NWIN / 2), dim3(512), 0, stream>>>(x, qkv_b, wbuf, wo_b, vscr, outp);
    } else {
        win_attn_np<<<dim3(NWIN), dim3(512), 0, stream>>>(
            x, qkv_w, qkv_b, wo_w, wo_b, bias_table, bias_index, outp);
    }
}

// Round 16
// 103.508 us; speedup vs baseline: 1.1363x; 1.0031x over previous
//
#include <hip/hip_runtime.h>
#include <cstdint>

namespace {
constexpr int NWIN = 4096;
constexpr int NT   = 49;
constexpr int D    = 128;
constexpr float SCALE = 0.17677669529663687f;  // 1/sqrt(32)

constexpr int SQ = 136;   // LDS row stride (ushorts)
constexpr int SV = 72;    // fallback kernel only

// wbuf layout (ushort element offsets)
constexpr size_t WQH   = 0;       // qkv_w hi frags (Q cols pre-scaled): 49152
constexpr size_t WOH   = 49152;   // wo_w hi frags: 16384
constexpr size_t WOL   = 65536;   // wo_w lo frags: 16384
constexpr size_t BFRAG = 81920;   // bias frags: 16384
constexpr size_t WBUF_BYTES = 98304 * 2;

// V-frag scratch: per window 8192 ushorts
constexpr size_t VSCR_OFF_USH = 98304;
constexpr size_t TOTAL_WS_BYTES = WBUF_BYTES + (size_t)NWIN * 8192 * 2;  // ~67.3 MB
}

using short8 = __attribute__((ext_vector_type(8))) short;
using f32x4  = __attribute__((ext_vector_type(4))) float;

__device__ __forceinline__ ushort f2bf(float x) {           // software RNE (prep/fallback)
    uint u = __builtin_bit_cast(uint, x);
    uint r = u + 0x7FFFu + ((u >> 16) & 1u);
    return (ushort)(r >> 16);
}
__device__ __forceinline__ ushort f2bf_tr(float x) {        // truncate (damped paths)
    return (ushort)(__builtin_bit_cast(uint, x) >> 16);
}
__device__ __forceinline__ float bf2f(ushort b) {
    uint u = ((uint)b) << 16;
    return __builtin_bit_cast(float, u);
}
__device__ __forceinline__ uint pack_bf2(float a, float b) { // software packed RNE (fallback)
    return ((uint)f2bf(a)) | (((uint)f2bf(b)) << 16);
}
// hardware packed RNE: dst = { lo: bf16(a), hi: bf16(b) } in ONE VALU op
__device__ __forceinline__ uint cvt_pk_bf16(float a, float b) {
    uint r;
    asm("v_cvt_pk_bf16_f32 %0, %1, %2" : "=v"(r) : "v"(a), "v"(b));
    return r;
}

// ---------------- prep: weight frags + bias frags ----------------
__global__ __launch_bounds__(256) void prep_all(
    const float* __restrict__ qkv_w, const float* __restrict__ wo_w,
    const float* __restrict__ bias_table, const int* __restrict__ bias_index,
    ushort* __restrict__ wbuf)
{
    const int blk = blockIdx.x, tid = threadIdx.x;
    if (blk < 96) {
        const int nt = blk >> 2, ks = blk & 3;
        for (int e = tid; e < 512; e += 256) {
            const int lane = e >> 3, j = e & 7;
            const int k = ks * 32 + (lane >> 4) * 8 + j;
            const int n = nt * 16 + (lane & 15);
            float wv = qkv_w[(size_t)k * 384 + n];
            if (n < 128) wv *= SCALE;
            wbuf[WQH + ((size_t)(nt * 4 + ks) * 64 + lane) * 8 + j] = f2bf(wv);
        }
    } else if (blk < 128) {
        const int b2 = blk - 96;
        const int nt = b2 >> 2, ks = b2 & 3;
        for (int e = tid; e < 512; e += 256) {
            const int lane = e >> 3, j = e & 7;
            const int k = ks * 32 + (lane >> 4) * 8 + j;
            const int n = nt * 16 + (lane & 15);
            const float wv = wo_w[(size_t)k * 128 + n];
            const ushort h = f2bf(wv);
            const size_t fo = ((size_t)(nt * 4 + ks) * 64 + lane) * 8 + j;
            wbuf[WOH + fo] = h;
            wbuf[WOL + fo] = f2bf(wv - bf2f(h));
        }
    } else {
        const int p = blk - 128;
        const int h = p >> 2, qt = p & 3;
        for (int ei = tid; ei < 1024; ei += 256) {
            const int lane = ei >> 4, t = (ei >> 2) & 3, r = ei & 3;
            const int q = qt * 16 + (lane & 15);
            const int k = 16 * t + 4 * (lane >> 4) + r;
            float v = 0.f;
            if (q < NT && k < NT) v = bias_table[bias_index[q * NT + k] * 4 + h];
            wbuf[BFRAG + (size_t)p * 1024 + ei] = f2bf(v);
        }
    }
}

// ---------------- fused kernel: 512 threads = 8 waves = TWO windows (R11 structure) ----------------
// phase 2: wave = (m = wid>>1, nt-half = wid&1), both windows share B-frags (AI=2)
// phase 3: wave = (win = wid>>2, head = wid&3), P in registers
// phase 4: wave = (win = wid>>2, ntp = wid&3 -> nt {ntp, ntp+4}), AI=4 on wo frags
// LDS = Q+K x 2 windows = 69632 B -> 2 blocks/CU. V via vscr (L2).
// R13 delta vs R11: all RNE bf16 conversions use hardware v_cvt_pk_bf16_f32.
__global__ __launch_bounds__(512, 4) void win2_fused(
    const float* __restrict__ x, const float* __restrict__ qkv_b,
    const ushort* __restrict__ wbuf, const float* __restrict__ wo_b,
    ushort* __restrict__ vscr, float* __restrict__ out)
{
    __shared__ __align__(16) ushort s_q[2][64 * SQ];   // Q (ph2-3), attn-out (ph3-4)
    __shared__ __align__(16) ushort s_k[2][64 * SQ];   // K

    const int b = blockIdx.x, tid = threadIdx.x;       // windows 2b, 2b+1
    const int wid = tid >> 6, lane = tid & 63;
    const int g = lane >> 4, lr = lane & 15;

    // ---- phase 0/2: QKV GEMM ----
    const int m = wid >> 1;          // token-quarter
    const int nt0 = (wid & 1) * 12;  // nt half

    short8 Ax[2][4];
    {
        const int row = m * 16 + lr;
        #pragma unroll
        for (int wi = 0; wi < 2; ++wi) {
            if (row < NT) {
                const float* xr = x + (size_t)(b * 2 + wi) * NT * D + row * D;
                #pragma unroll
                for (int ks = 0; ks < 4; ++ks) {
                    const float4 v0 = *reinterpret_cast<const float4*>(&xr[ks * 32 + g * 8]);
                    const float4 v1 = *reinterpret_cast<const float4*>(&xr[ks * 32 + g * 8 + 4]);
                    uint4 w;
                    w.x = cvt_pk_bf16(v0.x, v0.y); w.y = cvt_pk_bf16(v0.z, v0.w);
                    w.z = cvt_pk_bf16(v1.x, v1.y); w.w = cvt_pk_bf16(v1.z, v1.w);
                    Ax[wi][ks] = __builtin_bit_cast(short8, w);
                }
            } else {
                #pragma unroll
                for (int ks = 0; ks < 4; ++ks) Ax[wi][ks] = short8{0,0,0,0,0,0,0,0};
            }
        }
    }
    float qb[12];
    #pragma unroll
    for (int i = 0; i < 12; ++i) {
        const int nt = nt0 + i;
        float v = qkv_b[nt * 16 + lr];
        if (nt < 8) v *= SCALE;
        qb[i] = v;
    }

    #pragma unroll
    for (int pass = 0; pass < 4; ++pass) {     // 3 nt per pass
        const int ntb = nt0 + pass * 3;
        f32x4 acc[2][3] = {};
        #pragma unroll
        for (int ks = 0; ks < 4; ++ks) {
            short8 Bf[3];
            #pragma unroll
            for (int i = 0; i < 3; ++i)
                Bf[i] = *reinterpret_cast<const short8*>(
                    &wbuf[WQH + ((size_t)((ntb + i) * 4 + ks) * 64 + lane) * 8]);
            #pragma unroll
            for (int i = 0; i < 3; ++i) {
                acc[0][i] = __builtin_amdgcn_mfma_f32_16x16x32_bf16(Ax[0][ks], Bf[i], acc[0][i], 0, 0, 0);
                acc[1][i] = __builtin_amdgcn_mfma_f32_16x16x32_bf16(Ax[1][ks], Bf[i], acc[1][i], 0, 0, 0);
            }
        }
        // epilogue: Q (scaled, trunc) / K (trunc) -> LDS; V -> vscr frags (HW RNE)
        #pragma unroll
        for (int i = 0; i < 3; ++i) {
            const int nt = ntb + i;
            const int n = nt * 16 + lr;
            const float bias = qb[pass * 3 + i];
            #pragma unroll
            for (int wi = 0; wi < 2; ++wi) {
                if (nt < 16) {
                    ushort* const dst = (nt < 8) ? &s_q[wi][0] : &s_k[wi][0];
                    const int col = n & 127;
                    #pragma unroll
                    for (int jj = 0; jj < 4; ++jj)
                        dst[(m * 16 + g * 4 + jj) * SQ + col] = f2bf_tr(acc[wi][i][jj] + bias);
                } else {
                    const int d  = n - 256;
                    const int f  = ((d >> 5) * 2 + ((d >> 4) & 1)) * 2 + (m >> 1);
                    const int j0 = 4 * (m & 1);
                    const float b0 = acc[wi][i][0] + bias, b1 = acc[wi][i][1] + bias;
                    const float b2 = acc[wi][i][2] + bias, b3 = acc[wi][i][3] + bias;
                    uint2 hv;
                    hv.x = cvt_pk_bf16(b0, b1);
                    hv.y = cvt_pk_bf16(b2, b3);
                    ushort* const vw = vscr + (size_t)(b * 2 + wi) * 8192;
                    *reinterpret_cast<uint2*>(&vw[((size_t)f * 64 + lane) * 8 + j0]) = hv;
                }
            }
        }
    }
    __syncthreads();   // A: Q/K in LDS, V frags in vscr

    // ---- phase 3: wave = (wi3, h); 4 pairs (qt 0..3); P in registers ----
    const int wi3 = wid >> 2;
    const int h   = wid & 3;
    const ushort* const vwp = vscr + (size_t)(b * 2 + wi3) * 8192;
    f32x4 oac[4][2];
    {
        short8 Vf[2][2];
        #pragma unroll
        for (int dt = 0; dt < 2; ++dt)
            #pragma unroll
            for (int ks = 0; ks < 2; ++ks)
                Vf[dt][ks] = *reinterpret_cast<const short8*>(
                    &vwp[((size_t)(((h * 2 + dt) * 2) + ks) * 64 + lane) * 8]);

        #pragma unroll
        for (int pi = 0; pi < 4; ++pi) {
            const int qt = pi;
            const int p  = h * 4 + qt;
            const short8 Qf = *reinterpret_cast<const short8*>(&s_q[wi3][(qt * 16 + lr) * SQ + h * 32 + g * 8]);
            f32x4 sc[4];
            #pragma unroll
            for (int t = 0; t < 4; ++t) {
                const short8 Kf = *reinterpret_cast<const short8*>(&s_k[wi3][(t * 16 + lr) * SQ + h * 32 + g * 8]);
                f32x4 z = {};
                sc[t] = __builtin_amdgcn_mfma_f32_16x16x32_bf16(Kf, Qf, z, 0, 0, 0);
            }
            uint bw[8];
            {
                const uint4 b0 = *reinterpret_cast<const uint4*>(&wbuf[BFRAG + ((size_t)p * 64 + lane) * 16]);
                const uint4 b1 = *reinterpret_cast<const uint4*>(&wbuf[BFRAG + ((size_t)p * 64 + lane) * 16 + 8]);
                bw[0] = b0.x; bw[1] = b0.y; bw[2] = b0.z; bw[3] = b0.w;
                bw[4] = b1.x; bw[5] = b1.y; bw[6] = b1.z; bw[7] = b1.w;
            }
            float ev[16];
            float lsum = 0.f;
            #pragma unroll
            for (int t = 0; t < 4; ++t) {
                #pragma unroll
                for (int r = 0; r < 4; ++r) {
                    const int idx = 4 * t + r;
                    const uint bwv = bw[idx >> 1];
                    const float bv = __builtin_bit_cast(float, (idx & 1) ? (bwv & 0xFFFF0000u) : (bwv << 16));
                    float e;
                    if (t < 3) {
                        e = __expf(sc[t][r] + bv);
                    } else if (r == 0) {
                        e = (g == 0) ? __expf(sc[t][0] + bv) : 0.f;   // k=48 valid only at g==0
                    } else {
                        e = 0.f;
                    }
                    ev[idx] = e;
                    lsum += e;
                }
            }
            lsum += __shfl_xor(lsum, 16);
            lsum += __shfl_xor(lsum, 32);
            const float inv = 1.f / lsum;
            uint pw[8];
            #pragma unroll
            for (int i = 0; i < 8; ++i)
                pw[i] = cvt_pk_bf16(ev[2 * i] * inv, ev[2 * i + 1] * inv);   // HW RNE, normalized
            uint4 w0, w1;
            w0.x = pw[0]; w0.y = pw[1]; w0.z = pw[2]; w0.w = pw[3];
            w1.x = pw[4]; w1.y = pw[5]; w1.z = pw[6]; w1.w = pw[7];
            const short8 pa0 = __builtin_bit_cast(short8, w0);
            const short8 pa1 = __builtin_bit_cast(short8, w1);
            #pragma unroll
            for (int dt = 0; dt < 2; ++dt) {
                f32x4 o = {};
                o = __builtin_amdgcn_mfma_f32_16x16x32_bf16(pa0, Vf[dt][0], o, 0, 0, 0);
                o = __builtin_amdgcn_mfma_f32_16x16x32_bf16(pa1, Vf[dt][1], o, 0, 0, 0);
                oac[pi][dt] = o;
            }
        }
    }
    __syncthreads();   // C: all Q/K LDS reads done -> attn-out may overwrite Q

    #pragma unroll
    for (int pi = 0; pi < 4; ++pi) {
        #pragma unroll
        for (int dt = 0; dt < 2; ++dt) {
            const int d = h * 32 + dt * 16 + lr;
            #pragma unroll
            for (int r = 0; r < 4; r += 2) {
                const uint u = cvt_pk_bf16(oac[pi][dt][r], oac[pi][dt][r + 1]);  // HW RNE
                const int q0 = pi * 16 + 4 * g + r;
                s_q[wi3][q0 * SQ + d]       = (ushort)u;
                s_q[wi3][(q0 + 1) * SQ + d] = (ushort)(u >> 16);
            }
        }
    }
    __syncthreads();   // D: attn-out ready

    // ---- phase 4: out = attn @ wo_w + wo_b; wave = (wi4, nt {ntp, ntp+4}) ----
    {
        const int wi4 = wid >> 2;
        const int ntp = wid & 3;
        float wb2[2];
        wb2[0] = wo_b[ntp * 16 + lr];
        wb2[1] = wo_b[(ntp + 4) * 16 + lr];
        f32x4 acc[2][4] = {};
        #pragma unroll
        for (int ks = 0; ks < 4; ++ks) {
            short8 Ah[4];
            #pragma unroll
            for (int mm = 0; mm < 4; ++mm)
                Ah[mm] = *reinterpret_cast<const short8*>(&s_q[wi4][(mm * 16 + lr) * SQ + ks * 32 + g * 8]);
            #pragma unroll
            for (int i = 0; i < 2; ++i) {
                const int nt = ntp + i * 4;
                const size_t fo = ((size_t)(nt * 4 + ks) * 64 + lane) * 8;
                const short8 Wh = *reinterpret_cast<const short8*>(&wbuf[WOH + fo]);
                const short8 Wl = *reinterpret_cast<const short8*>(&wbuf[WOL + fo]);
                #pragma unroll
                for (int mm = 0; mm < 4; ++mm) {
                    acc[i][mm] = __builtin_amdgcn_mfma_f32_16x16x32_bf16(Ah[mm], Wh, acc[i][mm], 0, 0, 0);
                    acc[i][mm] = __builtin_amdgcn_mfma_f32_16x16x32_bf16(Ah[mm], Wl, acc[i][mm], 0, 0, 0);
                }
            }
        }
        float* ob = out + (size_t)(b * 2 + wi4) * NT * D;
        #pragma unroll
        for (int i = 0; i < 2; ++i) {
            const int n = (ntp + i * 4) * 16 + lr;
            #pragma unroll
            for (int mm = 0; mm < 4; ++mm) {
                #pragma unroll
                for (int jj = 0; jj < 4; ++jj) {
                    const int q = mm * 16 + 4 * g + jj;
                    if (q < NT) ob[q * D + n] = acc[i][mm][jj] + wb2[i];
                }
            }
        }
    }
}

// ---------------- fallback: fused kernel, no prep ----------------
__global__ __launch_bounds__(512, 4) void win_attn_np(
    const float* __restrict__ x,
    const float* __restrict__ qkv_w, const float* __restrict__ qkv_b,
    const float* __restrict__ wo_w,  const float* __restrict__ wo_b,
    const float* __restrict__ bias_table, const int* __restrict__ bias_index,
    float* __restrict__ out)
{
    __shared__ __align__(16) ushort s_all[26624];
    ushort* const s_qh = s_all;
    ushort* const s_kh = s_all + 8704;
    ushort* const s_vt = s_all + 17408;

    const int b = blockIdx.x, tid = threadIdx.x;
    const int wid = tid >> 6, lane = tid & 63;
    const int g = lane >> 4, lr = lane & 15;
    const int m = wid >> 1;
    const int nt0 = (wid & 1) * 12;
    const float* xb = x + (size_t)b * NT * D;

    short8 Ax[4];
    {
        const int row = m * 16 + lr;
        if (row < NT) {
            const float* xr = xb + row * D;
            #pragma unroll
            for (int ks = 0; ks < 4; ++ks) {
                const float4 v0 = *reinterpret_cast<const float4*>(&xr[ks * 32 + g * 8]);
                const float4 v1 = *reinterpret_cast<const float4*>(&xr[ks * 32 + g * 8 + 4]);
                uint4 w;
                w.x = pack_bf2(v0.x, v0.y); w.y = pack_bf2(v0.z, v0.w);
                w.z = pack_bf2(v1.x, v1.y); w.w = pack_bf2(v1.z, v1.w);
                Ax[ks] = __builtin_bit_cast(short8, w);
            }
        } else {
            #pragma unroll
            for (int ks = 0; ks < 4; ++ks) Ax[ks] = short8{0,0,0,0,0,0,0,0};
        }
    }
    float qb[12];
    #pragma unroll
    for (int i = 0; i < 12; ++i) {
        const int nt = nt0 + i;
        float v = qkv_b[nt * 16 + lr];
        if (nt < 8) v *= SCALE;
        qb[i] = v;
    }

    #pragma unroll
    for (int pass = 0; pass < 2; ++pass) {
        const int ntb = nt0 + pass * 6;
        f32x4 acc[6] = {};
        #pragma unroll
        for (int ks = 0; ks < 4; ++ks) {
            short8 Bf[6];
            #pragma unroll
            for (int i = 0; i < 6; ++i) {
                #pragma unroll
                for (int j = 0; j < 8; ++j) {
                    float wv = qkv_w[(size_t)(ks * 32 + g * 8 + j) * 384 + (ntb + i) * 16 + lr];
                    if (ntb + i < 8) wv *= SCALE;
                    Bf[i][j] = (short)f2bf(wv);
                }
            }
            #pragma unroll
            for (int i = 0; i < 6; ++i)
                acc[i] = __builtin_amdgcn_mfma_f32_16x16x32_bf16(Ax[ks], Bf[i], acc[i], 0, 0, 0);
        }
        #pragma unroll
        for (int i = 0; i < 6; ++i) {
            const int nt = ntb + i;
            const int n = nt * 16 + lr;
            const float bias = qb[pass * 6 + i];
            if (nt < 16) {
                ushort* const dst = (nt < 8) ? s_qh : s_kh;
                const int col = n & 127;
                #pragma unroll
                for (int jj = 0; jj < 4; ++jj) {
                    const int q = m * 16 + g * 4 + jj;
                    dst[q * SQ + col] = f2bf_tr(acc[i][jj] + bias);
                }
            } else {
                const int d = n - 256;
                const int cbase = 32 * (m >> 1) + 8 * ((4 * m + g) & 3) + 4 * (m & 1);
                ushort4 hv;
                #pragma unroll
                for (int jj = 0; jj < 4; ++jj)
                    (&hv.x)[jj] = f2bf(acc[i][jj] + bias);
                *reinterpret_cast<ushort4*>(&s_vt[d * SV + cbase]) = hv;
            }
        }
    }
    __syncthreads();

    {
        short8 pa[2][2];
        float inv2[2];
        #pragma unroll
        for (int pi = 0; pi < 2; ++pi) {
            const int p = wid * 2 + pi;
            const int h = p >> 2, qt = p & 3;
            uint bw[8];
            {
                const int q = qt * 16 + lr;
                #pragma unroll
                for (int t = 0; t < 4; ++t) {
                    #pragma unroll
                    for (int r = 0; r < 4; r += 2) {
                        const int k0 = 16 * t + 4 * g + r, k1 = k0 + 1;
                        float v0 = 0.f, v1 = 0.f;
                        if (q < NT && k0 < NT) v0 = bias_table[bias_index[q * NT + k0] * 4 + h];
                        if (q < NT && k1 < NT) v1 = bias_table[bias_index[q * NT + k1] * 4 + h];
                        bw[(4 * t + r) >> 1] = ((uint)f2bf(v0)) | (((uint)f2bf(v1)) << 16);
                    }
                }
            }
            const short8 Qf = *reinterpret_cast<const short8*>(&s_qh[(qt * 16 + lr) * SQ + h * 32 + g * 8]);
            f32x4 sc[4];
            #pragma unroll
            for (int t = 0; t < 4; ++t) {
                const short8 Kf = *reinterpret_cast<const short8*>(&s_kh[(t * 16 + lr) * SQ + h * 32 + g * 8]);
                f32x4 z = {};
                sc[t] = __builtin_amdgcn_mfma_f32_16x16x32_bf16(Kf, Qf, z, 0, 0, 0);
            }
            float lsum = 0.f;
            uint pw[8];
            #pragma unroll
            for (int t = 0; t < 4; ++t) {
                float ebits[4];
                #pragma unroll
                for (int r = 0; r < 4; ++r) {
                    const int idx = 4 * t + r;
                    const uint bwv = bw[idx >> 1];
                    const float bv = __builtin_bit_cast(float, (idx & 1) ? (bwv & 0xFFFF0000u) : (bwv << 16));
                    float e;
                    if (t < 3) {
                        e = __expf(sc[t][r] + bv);
                    } else if (r == 0) {
                        e = (g == 0) ? __expf(sc[t][0] + bv) : 0.f;
                    } else {
                        e = 0.f;
                    }
                    const uint tr = __builtin_bit_cast(uint, e) & 0xFFFF0000u;
                    ebits[r] = __builtin_bit_cast(float, tr);
                    lsum += ebits[r];
                }
                pw[t * 2 + 0] = (__builtin_bit_cast(uint, ebits[0]) >> 16) | (__builtin_bit_cast(uint, ebits[1]) & 0xFFFF0000u);
                pw[t * 2 + 1] = (__builtin_bit_cast(uint, ebits[2]) >> 16) | (__builtin_bit_cast(uint, ebits[3]) & 0xFFFF0000u);
            }
            lsum += __shfl_xor(lsum, 16);
            lsum += __shfl_xor(lsum, 32);
            inv2[pi] = 1.f / lsum;
            #pragma unroll
            for (int ks = 0; ks < 2; ++ks) {
                uint4 w;
                w.x = pw[(2 * ks) * 2 + 0]; w.y = pw[(2 * ks) * 2 + 1];
                w.z = pw[(2 * ks + 1) * 2 + 0]; w.w = pw[(2 * ks + 1) * 2 + 1];
                pa[pi][ks] = __builtin_bit_cast(short8, w);
            }
        }

        f32x4 oac[2][2];
        #pragma unroll
        for (int pi = 0; pi < 2; ++pi) {
            const int p = wid * 2 + pi;
            const int h = p >> 2;
            #pragma unroll
            for (int dt = 0; dt < 2; ++dt) {
                f32x4 o = {};
                #pragma unroll
                for (int ks = 0; ks < 2; ++ks) {
                    const short8 Vf = *reinterpret_cast<const short8*>(&s_vt[(h * 32 + dt * 16 + lr) * SV + ks * 32 + g * 8]);
                    o = __builtin_amdgcn_mfma_f32_16x16x32_bf16(pa[pi][ks], Vf, o, 0, 0, 0);
                }
                oac[pi][dt] = o;
            }
        }
        __syncthreads();

        #pragma unroll
        for (int pi = 0; pi < 2; ++pi) {
            const int p = wid * 2 + pi;
            const int h = p >> 2, qt = p & 3;
            #pragma unroll
            for (int dt = 0; dt < 2; ++dt) {
                const int d = h * 32 + dt * 16 + lr;
                #pragma unroll
                for (int r = 0; r < 4; ++r) {
                    const float inv = __shfl(inv2[pi], 4 * g + r);
                    const int q = qt * 16 + 4 * g + r;
                    s_qh[q * SQ + d] = f2bf(oac[pi][dt][r] * inv);
                }
            }
        }
    }
    __syncthreads();

    {
        const int nt04 = (wid & 1) * 4;
        float wb4[4];
        #pragma unroll
        for (int i = 0; i < 4; ++i) wb4[i] = wo_b[(nt04 + i) * 16 + lr];
        f32x4 acc[4] = {};
        #pragma unroll
        for (int ks = 0; ks < 4; ++ks) {
            short8 Wh[4], Wl[4];
            #pragma unroll
            for (int i = 0; i < 4; ++i) {
                #pragma unroll
                for (int j = 0; j < 8; ++j) {
                    const float wv = wo_w[(size_t)(ks * 32 + g * 8 + j) * 128 + (nt04 + i) * 16 + lr];
                    const ushort hh = f2bf(wv);
                    Wh[i][j] = (short)hh;
                    Wl[i][j] = (short)f2bf(wv - bf2f(hh));
                }
            }
            const short8 Ah = *reinterpret_cast<const short8*>(&s_qh[(m * 16 + lr) * SQ + ks * 32 + g * 8]);
            #pragma unroll
            for (int i = 0; i < 4; ++i) {
                acc[i] = __builtin_amdgcn_mfma_f32_16x16x32_bf16(Ah, Wh[i], acc[i], 0, 0, 0);
                acc[i] = __builtin_amdgcn_mfma_f32_16x16x32_bf16(Ah, Wl[i], acc[i], 0, 0, 0);
            }
        }
        float* ob = out + (size_t)b * NT * D;
        #pragma unroll
        for (int i = 0; i < 4; ++i) {
            const int n = (nt04 + i) * 16 + lr;
            #pragma unroll
            for (int jj = 0; jj < 4; ++jj) {
                const int q = m * 16 + g * 4 + jj;
                if (q < NT) ob[q * D + n] = acc[i][jj] + wb4[i];
            }
        }
    }
}

extern "C" void kernel_launch(void* const* d_in, const int* in_sizes, int n_in,
                              void* d_out, int out_size, void* d_ws, size_t ws_size,
                              hipStream_t stream) {
    const float* x          = (const float*)d_in[0];
    const float* qkv_w      = (const float*)d_in[1];
    const float* qkv_b      = (const float*)d_in[2];
    const float* wo_w       = (const float*)d_in[3];
    const float* wo_b       = (const float*)d_in[4];
    const float* bias_table = (const float*)d_in[5];
    const int*   bias_index = (const int*)d_in[6];
    float* outp = (float*)d_out;

    if (ws_size >= TOTAL_WS_BYTES) {
        ushort* wbuf = (ushort*)d_ws;
        ushort* vscr = wbuf + VSCR_OFF_USH;
        prep_all<<<dim3(144), dim3(256), 0, stream>>>(qkv_w, wo_w, bias_table, bias_index, wbuf);
        win2_fused<<<dim3(NWIN / 2), dim3(512), 0, stream>>>(x, qkv_b, wbuf, wo_b, vscr, outp);
    } else {
        win_attn_np<<<dim3(NWIN), dim3(512), 0, stream>>>(
            x, qkv_w, qkv_b, wo_w, wo_b, bias_table, bias_index, outp);
    }
}